// Round 5
// baseline (142.505 us; speedup 1.0000x reference)
//
#include <hip/hip_runtime.h>
#include <hip/hip_bf16.h>

// b=1, c=256, h=w=64 -> n=4096 pixels, 4 heads, hd=64, 32 groups x 8 ch.
// scale = hd^-0.5 * log2(e) = 0.18033688, folded into Wq (K0) and bq (K1
// epilogue) so attention softmax uses native v_exp_f32 (exp2) directly.
#define NPIX 4096
#define CCH  256
#define HD   64
#define GSIZE 32768   // 8 ch * 4096 pix per group

#define QSCALE 0.18033688f   // 0.125 * log2(e); softmax in base-2 domain

typedef __bf16 bf16x8 __attribute__((ext_vector_type(8)));
typedef __bf16 bf16x4 __attribute__((ext_vector_type(4)));
typedef __bf16 bf16x2 __attribute__((ext_vector_type(2)));
typedef float  f32x4  __attribute__((ext_vector_type(4)));
typedef unsigned int uint32x4 __attribute__((ext_vector_type(4)));

#define XPITCH 264   // X/F panel pitch (bf16) for K1/K3

#if __has_builtin(__builtin_amdgcn_exp2f)
#define EXP2(x) __builtin_amdgcn_exp2f(x)
#else
#define EXP2(x) __expf((x) * 0.6931471805599453f)
#endif

// MFMA 16x16x32_bf16 layouts (verified m89/m91):
//   A[m=lane&15][k=quad*8+j]; B[k=quad*8+j][n=lane&15]; C: row=quad*4+reg, col=lane&15

__device__ __forceinline__ unsigned pack_bf16x2(float lo, float hi)
{
    bf16x2 v;
    v[0] = (__bf16)lo;
    v[1] = (__bf16)hi;
    return __builtin_bit_cast(unsigned, v);
}

// ---------------------------------------------------------------------------
// K0: blocks 0..255: per-(group,1/8th) partial sums -> psum/pssq[256].
//     blocks 256..319: weight fp32->bf16 convert (Wq scaled by QSCALE).
// ---------------------------------------------------------------------------
__global__ __launch_bounds__(256) void stats_wconv(
    const float* __restrict__ X,
    const float* __restrict__ Wq, const float* __restrict__ Wk,
    const float* __restrict__ Wv, const float* __restrict__ Wp,
    float* __restrict__ psum, float* __restrict__ pssq, __bf16* __restrict__ Wb)
{
    const int bid = blockIdx.x, t = threadIdx.x;
    if (bid < 256) {
        const float* base = X + bid * 4096;   // (g = bid>>3, seg = bid&7)
        float sum = 0.f, ssq = 0.f;
        #pragma unroll
        for (int k = 0; k < 4; ++k) {
            float4 v = *(const float4*)(base + t * 4 + k * 1024);
            sum += v.x + v.y + v.z + v.w;
            ssq += v.x * v.x + v.y * v.y + v.z * v.z + v.w * v.w;
        }
        #pragma unroll
        for (int off = 1; off < 64; off <<= 1) {
            sum += __shfl_xor(sum, off);
            ssq += __shfl_xor(ssq, off);
        }
        __shared__ float red[2][4];
        const int wv = t >> 6;
        if ((t & 63) == 0) { red[0][wv] = sum; red[1][wv] = ssq; }
        __syncthreads();
        if (t == 0) {
            psum[bid] = red[0][0] + red[0][1] + red[0][2] + red[0][3];
            pssq[bid] = red[1][0] + red[1][1] + red[1][2] + red[1][3];
        }
    } else {
        const int j0 = (bid - 256) * 4096 + t * 16;
        const int m  = j0 >> 16;
        const float* W = (m == 0) ? Wq : (m == 1) ? Wk : (m == 2) ? Wv : Wp;
        const float sc = (m == 0) ? QSCALE : 1.f;
        const int off = j0 & 65535;
        #pragma unroll
        for (int k = 0; k < 4; ++k) {
            float4 v = *(const float4*)(W + off + k * 4);
            bf16x4 o;
            o[0] = (__bf16)(v.x * sc); o[1] = (__bf16)(v.y * sc);
            o[2] = (__bf16)(v.z * sc); o[3] = (__bf16)(v.w * sc);
            *(bf16x4*)(Wb + m * 65536 + off + k * 4) = o;
        }
    }
}

// ---------------------------------------------------------------------------
// K1: fused GroupNorm-apply + QKV MFMA GEMM. grid (64 pixblk, 6: z*2+och).
// (unchanged; qs = QSCALE)
// ---------------------------------------------------------------------------
__global__ __launch_bounds__(256) void gn_qkv(
    const float* __restrict__ X, const float* __restrict__ gamma,
    const float* __restrict__ beta,
    const float* __restrict__ psum, const float* __restrict__ pssq,
    const __bf16* __restrict__ Wb,
    const float* __restrict__ bq, const float* __restrict__ bk,
    const float* __restrict__ bv,
    __bf16* __restrict__ Qb, __bf16* __restrict__ Kb, __bf16* __restrict__ Vb)
{
    __shared__ __bf16 tile[64 * XPITCH];
    __shared__ float al[256], bl[256];

    const int t = threadIdx.x, lane = t & 63, wave = t >> 6;
    const int l16 = lane & 15, quad = lane >> 4;
    const int p0 = blockIdx.x * 64;
    const int z = blockIdx.y >> 1, och = blockIdx.y & 1;

    {
        const int g = t >> 3;
        float s = 0.f, q = 0.f;
        #pragma unroll
        for (int j = 0; j < 8; ++j) { s += psum[g * 8 + j]; q += pssq[g * 8 + j]; }
        const float mu  = s * (1.f / GSIZE);
        const float var = q * (1.f / GSIZE) - mu * mu;
        const float a = gamma[t] * rsqrtf(var + 1e-6f);
        al[t] = a;
        bl[t] = beta[t] - mu * a;
    }
    __syncthreads();

    #pragma unroll 4
    for (int i = 0; i < 16; ++i) {
        const int c4 = wave * 64 + i * 4;
        f32x4 a4 = *(const f32x4*)(al + c4);
        f32x4 b4 = *(const f32x4*)(bl + c4);
        bf16x4 pk;
        pk[0] = (__bf16)(X[(c4 + 0) * NPIX + p0 + lane] * a4[0] + b4[0]);
        pk[1] = (__bf16)(X[(c4 + 1) * NPIX + p0 + lane] * a4[1] + b4[1]);
        pk[2] = (__bf16)(X[(c4 + 2) * NPIX + p0 + lane] * a4[2] + b4[2]);
        pk[3] = (__bf16)(X[(c4 + 3) * NPIX + p0 + lane] * a4[3] + b4[3]);
        *(bf16x4*)(tile + lane * XPITCH + c4) = pk;
    }
    __syncthreads();

    const int pw = wave * 16;
    bf16x8 xf[8];
    #pragma unroll
    for (int kc = 0; kc < 8; ++kc)
        xf[kc] = *(const bf16x8*)(tile + (pw + l16) * XPITCH + kc * 32 + quad * 8);

    const __bf16* Wz = Wb + z * 65536;
    const float* bias = (z == 0) ? bq : (z == 1) ? bk : bv;

    if (z < 2) {
        const float qs = (z == 0) ? QSCALE : 1.f;
        __bf16* dst = (z == 0) ? Qb : Kb;
        #pragma unroll
        for (int grp = 0; grp < 2; ++grp) {
            f32x4 acc[4] = {};
            #pragma unroll
            for (int kc = 0; kc < 8; ++kc) {
                #pragma unroll
                for (int u = 0; u < 4; ++u) {
                    bf16x8 wf = *(const bf16x8*)(Wz + (och * 128 + (grp * 4 + u) * 16 + l16) * CCH + kc * 32 + quad * 8);
                    acc[u] = __builtin_amdgcn_mfma_f32_16x16x32_bf16(wf, xf[kc], acc[u], 0, 0, 0);
                }
            }
            #pragma unroll
            for (int u = 0; u < 4; ++u) {
                const int ot = och * 8 + grp * 4 + u;
                f32x4 bz = *(const f32x4*)(bias + och * 128 + (grp * 4 + u) * 16 + quad * 4);
                bf16x4 o;
                o[0] = (__bf16)(acc[u][0] + bz[0] * qs);
                o[1] = (__bf16)(acc[u][1] + bz[1] * qs);
                o[2] = (__bf16)(acc[u][2] + bz[2] * qs);
                o[3] = (__bf16)(acc[u][3] + bz[3] * qs);
                const int head = ot >> 2, dloc = (ot & 3) * 16 + quad * 4;
                *(bf16x4*)(dst + head * (NPIX * HD) + (p0 + pw + l16) * HD + dloc) = o;
            }
        }
    } else {
        #pragma unroll
        for (int grp = 0; grp < 2; ++grp) {
            f32x4 acc[4] = {};
            #pragma unroll
            for (int kc = 0; kc < 8; ++kc) {
                #pragma unroll
                for (int u = 0; u < 4; ++u) {
                    bf16x8 wf = *(const bf16x8*)(Wz + (och * 128 + (grp * 4 + u) * 16 + l16) * CCH + kc * 32 + quad * 8);
                    acc[u] = __builtin_amdgcn_mfma_f32_16x16x32_bf16(xf[kc], wf, acc[u], 0, 0, 0);
                }
            }
            #pragma unroll
            for (int u = 0; u < 4; ++u) {
                const int oc = och * 128 + (grp * 4 + u) * 16 + l16;
                const float bz = bias[oc];
                bf16x4 o;
                o[0] = (__bf16)(acc[u][0] + bz); o[1] = (__bf16)(acc[u][1] + bz);
                o[2] = (__bf16)(acc[u][2] + bz); o[3] = (__bf16)(acc[u][3] + bz);
                *(bf16x4*)(Vb + oc * NPIX + p0 + pw + quad * 4) = o;
            }
        }
    }
}

// ---------------------------------------------------------------------------
// K2 (R13): 128-q-row key-split zero-LDS attention -> fp32 partials.
// Diagnosis: all variants stuck at ~2900 cyc/tile-instance; MfmaUtil+VALUBusy
// ~39% (stall-bound). Theory: per-CU L2->L1 line-fill throughput — each
// (q-block x key-tile) pulls 256 unique 128B lines with zero reuse; MSHR-
// limited ~2000 cyc/tile. SW prefetch can't beat HW outstanding-miss cap
// (R12 null); 2nd wave shares the pool (R10/R11 null). Fix: DOUBLE q-rows
// per block (64->128) so each staged line serves 2x the MFMA work; split
// keys 2-way to keep 256 blocks = 256 CUs. Per-CU line-fills halve.
// bid&7 fixes (head, key-half) per XCD -> 512KB L2-resident working set.
// Partial/merge address convention identical to R11 (hardware-proven green);
// merge is fused into K3. Per-tile now: 72 MFMA, 64 exp2, 8 loads.
// ---------------------------------------------------------------------------
__global__ __launch_bounds__(256, 1) void attn_partial(
    const __bf16* __restrict__ Qb, const __bf16* __restrict__ Kb,
    const __bf16* __restrict__ Vb, float* __restrict__ Op,
    float* __restrict__ Lp)
{
    __shared__ __align__(16) float co[4 * 128 * 68];  // 139264 B merge buffer
    __shared__ float cl[4 * 128];

    const int t = threadIdx.x, lane = t & 63, wave = t >> 6;
    const int l16 = lane & 15, quad = lane >> 4;

    const int bid  = blockIdx.x;
    const int head = (bid & 7) >> 1;       // bits 1-2: head (XCD pinning)
    const int half = bid & 1;              // bit 0: key half (XCD pinning)
    const int qt   = bid >> 3;             // 0..31: q-tile of 128 rows
    const int p0   = qt * 128;
    const int kt0  = half * 16;            // this block's 16 key-tiles

    const __bf16* Qh = Qb + head * (NPIX * HD);
    const __bf16* Kh = Kb + head * (NPIX * HD) + (wave * 32 + l16) * HD + quad * 8;
    const __bf16* Vh = Vb + head * (HD * NPIX) + l16 * NPIX + wave * 32 + quad * 8;

    // Q B-frags for 128 shared rows: B[k=d][n=row16]
    bf16x8 qf[8][2];
    #pragma unroll
    for (int rt = 0; rt < 8; ++rt) {
        const __bf16* qp = Qh + (p0 + rt * 16 + l16) * HD + quad * 8;
        qf[rt][0] = *(const bf16x8*)(qp);
        qf[rt][1] = *(const bf16x8*)(qp + 32);
    }

    bf16x8 ones;
    #pragma unroll
    for (int j = 0; j < 8; ++j) ones[j] = (__bf16)1.0f;

    f32x4 l_acc[8] = {};
    f32x4 o_acc[4][8] = {};   // [dt][rt]

    // load tile 'it' into one named buffer set (8 x global_load_dwordx4)
    auto ldKV = [&](int it,
                    bf16x8& k0, bf16x8& k1, bf16x8& k2, bf16x8& k3,
                    bf16x8& v0, bf16x8& v1, bf16x8& v2, bf16x8& v3) {
        const __bf16* kp = Kh + it * (128 * HD);
        k0 = *(const bf16x8*)(kp);
        k1 = *(const bf16x8*)(kp + 32);
        k2 = *(const bf16x8*)(kp + 16 * HD);
        k3 = *(const bf16x8*)(kp + 16 * HD + 32);
        const __bf16* vp = Vh + it * 128;
        v0 = *(const bf16x8*)(vp);
        v1 = *(const bf16x8*)(vp + 16 * NPIX);
        v2 = *(const bf16x8*)(vp + 32 * NPIX);
        v3 = *(const bf16x8*)(vp + 48 * NPIX);
    };

    auto step = [&](bf16x8 k0, bf16x8 k1, bf16x8 k2, bf16x8 k3,
                    bf16x8 v0, bf16x8 v1, bf16x8 v2, bf16x8 v3) {
        // two rt-halves: rtb=1's QK MFMAs can overlap rtb=0's exp chain
        #pragma unroll
        for (int rtb = 0; rtb < 2; ++rtb) {
            // S^T = K Q^T : C(key_local = kt*16+quad*4+r, row = r16)
            f32x4 st0[4] = {}, st1[4] = {};
            #pragma unroll
            for (int rt = 0; rt < 4; ++rt) {
                const int r = rtb * 4 + rt;
                st0[rt] = __builtin_amdgcn_mfma_f32_16x16x32_bf16(k0, qf[r][0], st0[rt], 0, 0, 0);
                st0[rt] = __builtin_amdgcn_mfma_f32_16x16x32_bf16(k1, qf[r][1], st0[rt], 0, 0, 0);
                st1[rt] = __builtin_amdgcn_mfma_f32_16x16x32_bf16(k2, qf[r][0], st1[rt], 0, 0, 0);
                st1[rt] = __builtin_amdgcn_mfma_f32_16x16x32_bf16(k3, qf[r][1], st1[rt], 0, 0, 0);
            }
            #pragma unroll
            for (int rt = 0; rt < 4; ++rt) {
                const int r = rtb * 4 + rt;
                // P = 2^(S'); a0/a1 = kt0 keys, b0/b1 = kt1 keys
                unsigned a0 = pack_bf16x2(EXP2(st0[rt][0]), EXP2(st0[rt][1]));
                unsigned a1 = pack_bf16x2(EXP2(st0[rt][2]), EXP2(st0[rt][3]));
                unsigned b0 = pack_bf16x2(EXP2(st1[rt][0]), EXP2(st1[rt][1]));
                unsigned b1 = pack_bf16x2(EXP2(st1[rt][2]), EXP2(st1[rt][3]));
                // swap32 then swap16: (a0,b0) -> (w0,w2); (a1,b1) -> (w1,w3)
                asm("v_permlane32_swap_b32 %0, %1" : "+v"(a0), "+v"(b0));
                asm("v_permlane32_swap_b32 %0, %1" : "+v"(a1), "+v"(b1));
                asm("v_permlane16_swap_b32 %0, %1" : "+v"(a0), "+v"(b0));
                asm("v_permlane16_swap_b32 %0, %1" : "+v"(a1), "+v"(b1));
                uint32x4 w;
                w[0] = a0; w[1] = a1; w[2] = b0; w[3] = b1;
                const bf16x8 bp = __builtin_bit_cast(bf16x8, w);  // B[k=key32][n=row]
                l_acc[r] = __builtin_amdgcn_mfma_f32_16x16x32_bf16(ones, bp, l_acc[r], 0, 0, 0);
                o_acc[0][r] = __builtin_amdgcn_mfma_f32_16x16x32_bf16(v0, bp, o_acc[0][r], 0, 0, 0);
                o_acc[1][r] = __builtin_amdgcn_mfma_f32_16x16x32_bf16(v1, bp, o_acc[1][r], 0, 0, 0);
                o_acc[2][r] = __builtin_amdgcn_mfma_f32_16x16x32_bf16(v2, bp, o_acc[2][r], 0, 0, 0);
                o_acc[3][r] = __builtin_amdgcn_mfma_f32_16x16x32_bf16(v3, bp, o_acc[3][r], 0, 0, 0);
            }
        }
    };

    // 1-deep register double-buffer over this block's 16 key-tiles
    bf16x8 ka0, ka1, ka2, ka3, va0, va1, va2, va3;
    bf16x8 kb0, kb1, kb2, kb3, vb0, vb1, vb2, vb3;

    ldKV(kt0, ka0, ka1, ka2, ka3, va0, va1, va2, va3);
    #pragma unroll 1
    for (int it = 0; it < 16; it += 2) {
        ldKV(kt0 + it + 1, kb0, kb1, kb2, kb3, vb0, vb1, vb2, vb3);
        step(ka0, ka1, ka2, ka3, va0, va1, va2, va3);
        if (it + 2 < 16)
            ldKV(kt0 + it + 2, ka0, ka1, ka2, ka3, va0, va1, va2, va3);
        step(kb0, kb1, kb2, kb3, vb0, vb1, vb2, vb3);
    }

    // ---- in-LDS 4-way wave (key sub-slice) merge, then fp32 partial store ----
    #pragma unroll
    for (int dt = 0; dt < 4; ++dt)
        #pragma unroll
        for (int rt = 0; rt < 8; ++rt)
            *(f32x4*)(co + wave * 8704 + (rt * 16 + l16) * 68 + dt * 16 + quad * 4) = o_acc[dt][rt];
    if (quad == 0) {
        #pragma unroll
        for (int rt = 0; rt < 8; ++rt)
            cl[wave * 128 + rt * 16 + l16] = l_acc[rt][0];
    }
    __syncthreads();

    {
        const int row = t >> 1, dhalf = t & 1, dc = dhalf * 32;
        f32x4 s[8];
        #pragma unroll
        for (int j = 0; j < 8; ++j) {
            s[j] = f32x4{0.f, 0.f, 0.f, 0.f};
            #pragma unroll
            for (int w = 0; w < 4; ++w)
                s[j] += *(const f32x4*)(co + w * 8704 + row * 68 + dc + j * 4);
        }
        // un-normalized fp32 partial, R11-proven address convention
        float* dsto = Op + half * (NPIX * CCH) + (p0 + row) * CCH + head * HD + dc;
        #pragma unroll
        for (int j = 0; j < 8; ++j)
            *(f32x4*)(dsto + j * 4) = s[j];
        if (dhalf == 0) {
            const float l = cl[row] + cl[128 + row] + cl[256 + row] + cl[384 + row];
            Lp[half * 16384 + head * 4096 + p0 + row] = l;
        }
    }
}

// ---------------------------------------------------------------------------
// K3 (R13): proj GEMM with fused key-half merge in the staging loop.
// Reads the two fp32 partials + Lp, normalizes (identical per-element math
// to R11's proven attn_merge: P = idx>>8, head = (idx>>6)&3), packs bf16
// into LDS. GEMM body unchanged.
// ---------------------------------------------------------------------------
__global__ __launch_bounds__(256) void gemm_proj(
    const float* __restrict__ Op, const float* __restrict__ Lp,
    const __bf16* __restrict__ Wpb,
    const float* __restrict__ bias, const float* __restrict__ X,
    float* __restrict__ Out)
{
    __shared__ __bf16 Bs[32 * XPITCH];

    const int t = threadIdx.x, lane = t & 63, wave = t >> 6;
    const int l16 = lane & 15, quad = lane >> 4;
    const int p0  = blockIdx.x * 32;
    const int och = blockIdx.y;

    #pragma unroll
    for (int pg = 0; pg < 4; ++pg) {
        const int col  = p0 + pg * 8;
        const int gidx = t * NPIX + col;          // linear idx in F-space
        const int P    = gidx >> 8;               // q-row (R11-proven decode)
        const int hd8  = (gidx >> 6) & 3;         // head, constant across j
        const float l  = Lp[hd8 * 4096 + P] + Lp[16384 + hd8 * 4096 + P];
        const float inv = 1.f / l;
        f32x4 a0 = *(const f32x4*)(Op + gidx);
        f32x4 a1 = *(const f32x4*)(Op + gidx + 4);
        f32x4 b0 = *(const f32x4*)(Op + NPIX * CCH + gidx);
        f32x4 b1 = *(const f32x4*)(Op + NPIX * CCH + gidx + 4);
        #pragma unroll
        for (int j = 0; j < 4; ++j) {
            Bs[(pg * 8 + j) * XPITCH + t]       = (__bf16)((a0[j] + b0[j]) * inv);
            Bs[(pg * 8 + j + 4) * XPITCH + t]   = (__bf16)((a1[j] + b1[j]) * inv);
        }
    }
    __syncthreads();

    const int pixset = wave & 1, ocset = wave >> 1;
    bf16x8 af[8];
    #pragma unroll
    for (int kc = 0; kc < 8; ++kc)
        af[kc] = *(const bf16x8*)(Bs + (pixset * 16 + l16) * XPITCH + kc * 32 + quad * 8);

    #pragma unroll
    for (int u = 0; u < 4; ++u) {
        f32x4 acc = {};
        const int oc_t = och * 128 + ocset * 64 + u * 16;
        #pragma unroll
        for (int kc = 0; kc < 8; ++kc) {
            bf16x8 wf = *(const bf16x8*)(Wpb + (oc_t + l16) * CCH + kc * 32 + quad * 8);
            acc = __builtin_amdgcn_mfma_f32_16x16x32_bf16(af[kc], wf, acc, 0, 0, 0);
        }
        const int oc  = oc_t + l16;
        const int pix = p0 + pixset * 16 + quad * 4;
        const float bz = bias[oc];
        f32x4 r4 = *(const f32x4*)(X + oc * NPIX + pix);
        f32x4 y;
        y[0] = acc[0] + bz + r4[0];
        y[1] = acc[1] + bz + r4[1];
        y[2] = acc[2] + bz + r4[2];
        y[3] = acc[3] + bz + r4[3];
        *(f32x4*)(Out + oc * NPIX + pix) = y;
    }
}

// ---------------------------------------------------------------------------
extern "C" void kernel_launch(void* const* d_in, const int* in_sizes, int n_in,
                              void* d_out, int out_size, void* d_ws, size_t ws_size,
                              hipStream_t stream)
{
    const float* x     = (const float*)d_in[0];
    const float* gamma = (const float*)d_in[1];
    const float* beta  = (const float*)d_in[2];
    const float* Wq    = (const float*)d_in[3];
    const float* bq    = (const float*)d_in[4];
    const float* Wk    = (const float*)d_in[5];
    const float* bk    = (const float*)d_in[6];
    const float* Wv    = (const float*)d_in[7];
    const float* bv    = (const float*)d_in[8];
    const float* Wp    = (const float*)d_in[9];
    const float* bp    = (const float*)d_in[10];
    float* out = (float*)d_out;

    char* ws = (char*)d_ws;
    float*  psum = (float*)(ws);                // 1KB stats partial sums
    float*  pssq = (float*)(ws + 1024);         // 1KB
    __bf16* Wb   = (__bf16*)(ws + 65536);       // 512KB bf16 4x[256][256]
    __bf16* Qb   = (__bf16*)(ws + (1 << 20));   // 2MB bf16 [head][pix][64]
    __bf16* Kb   = (__bf16*)(ws + (3 << 20));   // 2MB bf16 [head][pix][64]
    __bf16* Vb   = (__bf16*)(ws + (5 << 20));   // 2MB bf16 [c][pix]
    float*  Op   = (float*)(ws + (16 << 20));   // 8MB f32 2x key-half partials
    float*  Lp   = (float*)(ws + (25 << 20));   // 128KB f32 2x[head][pix] sums

    stats_wconv<<<320, 256, 0, stream>>>(x, Wq, Wk, Wv, Wp, psum, pssq, Wb);

    dim3 gq(64, 6);
    gn_qkv<<<gq, 256, 0, stream>>>(x, gamma, beta, psum, pssq, Wb,
                                   bq, bk, bv, Qb, Kb, Vb);

    attn_partial<<<256, 256, 0, stream>>>(Qb, Kb, Vb, Op, Lp);

    dim3 gp(128, 2);
    gemm_proj<<<gp, 256, 0, stream>>>(Op, Lp, Wb + 3 * 65536, bp, x, out);
}